// Round 10
// baseline (1600.303 us; speedup 1.0000x reference)
//
#include <hip/hip_runtime.h>
#include <math.h>

#define T_ 4096
#define D_ 128
#define R_ 8

typedef float f32x4 __attribute__((ext_vector_type(4)));
typedef _Float16 f16x8 __attribute__((ext_vector_type(8)));
typedef unsigned short u16x8 __attribute__((ext_vector_type(8)));

__device__ __forceinline__ unsigned short f2h_bits(float f) {
    _Float16 h = (_Float16)f;
    return __builtin_bit_cast(unsigned short, h);
}

__device__ __forceinline__ unsigned long long pack4h(float a, float b, float c, float d) {
    unsigned int lo = __builtin_bit_cast(unsigned int, __builtin_amdgcn_cvt_pkrtz(a, b));
    unsigned int hi = __builtin_bit_cast(unsigned int, __builtin_amdgcn_cvt_pkrtz(c, d));
    return ((unsigned long long)hi << 32) | (unsigned long long)lo;
}

// tanh(x) = 1 - 2/(exp2(2*log2e*x)+1); large-|x| safe
__device__ __forceinline__ float tanh_fast(float x) {
    float e = __builtin_amdgcn_exp2f(x * 2.885390082f);
    float r = __builtin_amdgcn_rcpf(e + 1.0f);
    return fmaf(-2.0f, r, 1.0f);
}

// tanh-approx GELU: |err| ~1e-3 vs erf form (budget is 2%)
__device__ __forceinline__ float gelu_fast(float x) {
    float x2 = x * x;
    float u = x * fmaf(x2, 0.044715f, 1.0f);
    float e = __builtin_amdgcn_exp2f(u * -2.3022082f);
    return x * __builtin_amdgcn_rcpf(1.0f + e);
}

__device__ __forceinline__ float gelu_exact(float x) {
    return 0.5f * x * (1.0f + erff(x * 0.7071067811865475f));
}

// ---------------------------------------------------------------------------
// Selector MLPs (tiny): hdr[0]=n_evolve, hdr[1]=alpha, hdr[2..9]=rule_weights
// ---------------------------------------------------------------------------
__global__ void selectors_kernel(
    const float* __restrict__ c,
    const float* __restrict__ rW1, const float* __restrict__ rb1,
    const float* __restrict__ rW2, const float* __restrict__ rb2,
    const float* __restrict__ sW1, const float* __restrict__ sb1,
    const float* __restrict__ sW2, const float* __restrict__ sb2,
    const float* __restrict__ aW1, const float* __restrict__ ab1,
    const float* __restrict__ aW2, const float* __restrict__ ab2,
    float* __restrict__ hdr)
{
    __shared__ float cs[128];
    __shared__ float hb[64];
    __shared__ float lg[8];
    const int l = threadIdx.x;  // 64 threads
    cs[l] = c[l];
    cs[l + 64] = c[l + 64];
    __syncthreads();

    // rule selector: 128 -> 64 -> 8 -> softmax
    {
        float acc = rb1[l];
        for (int k = 0; k < 128; ++k) acc += cs[k] * rW1[k * 64 + l];
        hb[l] = gelu_exact(acc);
    }
    __syncthreads();
    if (l < 8) {
        float acc = rb2[l];
        for (int j = 0; j < 64; ++j) acc += hb[j] * rW2[j * 8 + l];
        lg[l] = acc;
    }
    __syncthreads();
    if (l == 0) {
        float mx = lg[0];
        for (int o = 1; o < 8; ++o) mx = fmaxf(mx, lg[o]);
        float e[8], se = 0.0f;
        for (int o = 0; o < 8; ++o) { e[o] = expf(lg[o] - mx); se += e[o]; }
        for (int o = 0; o < 8; ++o) hdr[2 + o] = e[o] / se;
    }
    __syncthreads();

    // steps selector: 128 -> 32 -> 7 -> softmax -> n_evolve
    if (l < 32) {
        float acc = sb1[l];
        for (int k = 0; k < 128; ++k) acc += cs[k] * sW1[k * 32 + l];
        hb[l] = gelu_exact(acc);
    }
    __syncthreads();
    if (l < 7) {
        float acc = sb2[l];
        for (int j = 0; j < 32; ++j) acc += hb[j] * sW2[j * 7 + l];
        lg[l] = acc;
    }
    __syncthreads();
    if (l == 0) {
        float mx = lg[0];
        for (int o = 1; o < 7; ++o) mx = fmaxf(mx, lg[o]);
        float e[7], se = 0.0f;
        for (int o = 0; o < 7; ++o) { e[o] = expf(lg[o] - mx); se += e[o]; }
        float n_soft = 0.0f;
        for (int o = 0; o < 7; ++o) n_soft += (e[o] / se) * (float)(2 + o);
        int ne = (int)floorf(n_soft + 0.5f);
        ne = ne < 2 ? 2 : (ne > 8 ? 8 : ne);
        hdr[0] = (float)ne;
    }
    __syncthreads();

    // alpha selector: 128 -> 32 -> 1 -> sigmoid
    if (l < 32) {
        float acc = ab1[l];
        for (int k = 0; k < 128; ++k) acc += cs[k] * aW1[k * 32 + l];
        hb[l] = gelu_exact(acc);
    }
    __syncthreads();
    if (l == 0) {
        float acc = ab2[0];
        for (int j = 0; j < 32; ++j) acc += hb[j] * aW2[j];
        hdr[1] = 0.1f + 0.8f / (1.0f + expf(-acc));
    }
}

// ---------------------------------------------------------------------------
// Weight prep, coalesced: lane -> n (contiguous source reads), each thread
// packs 8 consecutive k into one b128 store.
// ---------------------------------------------------------------------------
__global__ __launch_bounds__(256) void prep_weights(
    const float* __restrict__ W1, const float* __restrict__ W2,
    unsigned short* __restrict__ W1T, unsigned short* __restrict__ W2T)
{
    const int bx = blockIdx.x;
    if (bx < 384) {
        const int r = bx / 48;
        const int k0 = (bx % 48) * 8;
        const int n = threadIdx.x;          // 0..255
        u16x8 v;
#pragma unroll
        for (int j = 0; j < 8; ++j)
            v[j] = f2h_bits(W1[((size_t)r * 384 + k0 + j) * 256 + n]);
        *reinterpret_cast<u16x8*>(W1T + ((size_t)r * 256 + n) * 384 + k0) = v;
    } else {
        const int b2 = bx - 384;
        const int r = b2 / 32;
        const int k0 = (b2 % 32) * 8;
        const int n = threadIdx.x;
        if (n < 128) {
            u16x8 v;
#pragma unroll
            for (int j = 0; j < 8; ++j)
                v[j] = f2h_bits(W2[((size_t)r * 256 + k0 + j) * 128 + n]);
            *reinterpret_cast<u16x8*>(W2T + ((size_t)r * 128 + n) * 256 + k0) = v;
        }
    }
}

// ---------------------------------------------------------------------------
// One evolution step, rule-split WITHOUT atomics.
// Grid = 1024 = 512 tiles x 2 groups (rules 0..3 / 4..7). Block = 256 thr
// (4 waves), tile = 64 rows, LDS 49.7 KB -> 3 blocks/CU (145 KB), 12 waves/CU.
// launch_bounds(256,3): VGPR cap 170; xfr/hfr single-buffered (LDS latency is
// short + lgkm-pipelined), weight loads depth-1 double-buffered (L2 latency
// covered by the 16-MFMA cluster). Group 0 -> dst (with alpha*x residual),
// group 1 -> p1 partial; combine kernel adds them.
// ---------------------------------------------------------------------------
__global__ __launch_bounds__(256, 3) void evolve_step(
    int step,
    const float* __restrict__ cells_in,
    float* __restrict__ buf0,
    float* __restrict__ buf1,
    float* __restrict__ p1,
    const unsigned short* __restrict__ W1T,
    const unsigned short* __restrict__ W2T,
    const float* __restrict__ b1,
    const float* __restrict__ b2,
    const float* __restrict__ hdr)
{
    if (step >= (int)hdr[0]) return;
    const float* src = (step == 0) ? cells_in : ((step & 1) ? buf0 : buf1);
    float* dst = (step & 1) ? buf1 : buf0;
    const float alpha = hdr[1];

    // X tile: rows t0-1 .. t0+64 (66 x 128 fp16), XOR-swizzled
    __shared__ __align__(16) unsigned short Xs[66 * 128];
    // H tile: 64 x 256 fp16, XOR-swizzled
    __shared__ __align__(16) unsigned short Hs[64 * 256];

    const int tid = threadIdx.x;
    const int blk = blockIdx.x;
    const int group = blk & 1;          // 0 -> rules 0..3, 1 -> rules 4..7
    const int tile = blk >> 1;
    const int b = tile >> 6;
    const int t0 = (tile & 63) << 6;
    const float* srcb = src + (size_t)b * (T_ * D_);

    // ---- stage X tile (float4 load -> pack4h -> b64 swizzled store) ----
    {
        const int cr = (tid & 31) << 2;
        for (int j = (tid >> 5); j < 66; j += 8) {
            const int tg = (t0 + j - 1) & (T_ - 1);
            const f32x4 v = *reinterpret_cast<const f32x4*>(srcb + tg * D_ + cr);
            int byte = (j * 128 + cr) * 2;
            byte ^= (j & 7) << 4;
            *reinterpret_cast<unsigned long long*>(reinterpret_cast<char*>(Xs) + byte) =
                pack4h(v[0], v[1], v[2], v[3]);
        }
    }
    __syncthreads();

    const int wave = tid >> 6;
    const int lane = tid & 63;
    const int l16 = lane & 15;
    const int lhi = lane >> 4;
    const int kbase = lhi * 8;
    const char* Xsb = reinterpret_cast<const char*>(Xs);
    const char* Hsb = reinterpret_cast<const char*>(Hs);

    const f32x4 z4 = {0.0f, 0.0f, 0.0f, 0.0f};
    f32x4 facc[2][4];   // [nf2][tf]
#pragma unroll
    for (int a = 0; a < 2; ++a)
#pragma unroll
        for (int bq = 0; bq < 4; ++bq) facc[a][bq] = z4;

    for (int j = 0; j < 4; ++j) {
        const int r = group * 4 + j;
        // -------- GEMM1: H^T = W1^T X^T (wave owns H cols [64w, 64w+64)) ----
        f32x4 acc1[4][4];   // [nf][tf]
#pragma unroll
        for (int a = 0; a < 4; ++a)
#pragma unroll
            for (int bq = 0; bq < 4; ++bq) acc1[a][bq] = z4;

        const unsigned short* w1r = W1T + (size_t)r * (256 * 384);

        f16x8 wfr[2][4];
        // prologue: weights kk = 0 into buffer 0
#pragma unroll
        for (int nf = 0; nf < 4; ++nf)
            wfr[0][nf] = __builtin_bit_cast(f16x8, *reinterpret_cast<const u16x8*>(
                w1r + (size_t)(wave * 64 + nf * 16 + l16) * 384 + kbase));

#pragma unroll
        for (int kk = 0; kk < 12; ++kk) {
            const int cur = kk & 1;
            const int nxt = cur ^ 1;
            // prefetch next weight fragments (global, L2)
            if (kk < 11) {
                const int kgn = (kk + 1) * 32 + kbase;
#pragma unroll
                for (int nf = 0; nf < 4; ++nf)
                    wfr[nxt][nf] = __builtin_bit_cast(f16x8, *reinterpret_cast<const u16x8*>(
                        w1r + (size_t)(wave * 64 + nf * 16 + l16) * 384 + kgn));
            }
            // current X fragments from LDS (single-buffered)
            const int seg = kk >> 2;
            const int rowadd = (seg == 0) ? 1 : ((seg == 1) ? 0 : 2);
            const int kloc = ((kk & 3) * 32 + kbase) * 2;
            f16x8 xfr[4];
#pragma unroll
            for (int tf = 0; tf < 4; ++tf) {
                const int row = tf * 16 + l16 + rowadd;
                int byte = row * 256 + kloc;
                byte ^= (row & 7) << 4;
                xfr[tf] = __builtin_bit_cast(f16x8,
                    *reinterpret_cast<const u16x8*>(Xsb + byte));
            }
#pragma unroll
            for (int nf = 0; nf < 4; ++nf)
#pragma unroll
                for (int tf = 0; tf < 4; ++tf)
                    acc1[nf][tf] = __builtin_amdgcn_mfma_f32_16x16x32_f16(
                        wfr[cur][nf], xfr[tf], acc1[nf][tf], 0, 0, 0);
        }

        __syncthreads();   // previous rule's GEMM2 reads of Hs complete

        // bias + GELU -> Hs. Lane holds row t, cols n0..n0+3 -> b64 write
#pragma unroll
        for (int tf = 0; tf < 4; ++tf) {
            const int t = tf * 16 + l16;
            const int rowbyte = t * 512;
            const int swz = (t & 7) << 4;
#pragma unroll
            for (int nf = 0; nf < 4; ++nf) {
                const f32x4 bv = *reinterpret_cast<const f32x4*>(
                    b1 + r * 256 + wave * 64 + nf * 16 + lhi * 4);
                const f32x4 a = acc1[nf][tf];
                const float g0 = gelu_fast(a[0] + bv[0]);
                const float g1 = gelu_fast(a[1] + bv[1]);
                const float g2 = gelu_fast(a[2] + bv[2]);
                const float g3 = gelu_fast(a[3] + bv[3]);
                int byte = rowbyte + wave * 128 + nf * 32 + lhi * 8;
                byte ^= swz;
                *reinterpret_cast<unsigned long long*>(reinterpret_cast<char*>(Hs) + byte) =
                    pack4h(g0, g1, g2, g3);
            }
        }
        __syncthreads();

        // -------- GEMM2: O^T = W2^T H^T (wave owns O cols [32w, 32w+32)) ----
        f32x4 acc2[2][4];   // [nf2][tf]
#pragma unroll
        for (int a = 0; a < 2; ++a)
#pragma unroll
            for (int bq = 0; bq < 4; ++bq) acc2[a][bq] = z4;

        const unsigned short* w2r = W2T + (size_t)r * (128 * 256);

        f16x8 wfr2[2][2];
        // prologue k2 = 0
#pragma unroll
        for (int nf2 = 0; nf2 < 2; ++nf2)
            wfr2[0][nf2] = __builtin_bit_cast(f16x8, *reinterpret_cast<const u16x8*>(
                w2r + (size_t)(wave * 32 + nf2 * 16 + l16) * 256 + kbase));

#pragma unroll
        for (int k2 = 0; k2 < 8; ++k2) {
            const int cur = k2 & 1;
            const int nxt = cur ^ 1;
            if (k2 < 7) {
                const int kgn = (k2 + 1) * 32 + kbase;
#pragma unroll
                for (int nf2 = 0; nf2 < 2; ++nf2)
                    wfr2[nxt][nf2] = __builtin_bit_cast(f16x8, *reinterpret_cast<const u16x8*>(
                        w2r + (size_t)(wave * 32 + nf2 * 16 + l16) * 256 + kgn));
            }
            const int kg2 = (k2 * 32 + kbase) * 2;
            f16x8 hfr[4];
#pragma unroll
            for (int tf = 0; tf < 4; ++tf) {
                const int t = tf * 16 + l16;
                int byte = t * 512 + kg2;
                byte ^= (t & 7) << 4;
                hfr[tf] = __builtin_bit_cast(f16x8,
                    *reinterpret_cast<const u16x8*>(Hsb + byte));
            }
#pragma unroll
            for (int nf2 = 0; nf2 < 2; ++nf2)
#pragma unroll
                for (int tf = 0; tf < 4; ++tf)
                    acc2[nf2][tf] = __builtin_amdgcn_mfma_f32_16x16x32_f16(
                        wfr2[cur][nf2], hfr[tf], acc2[nf2][tf], 0, 0, 0);
        }

        const float rw = hdr[2 + r];
#pragma unroll
        for (int nf2 = 0; nf2 < 2; ++nf2) {
            const f32x4 bv = *reinterpret_cast<const f32x4*>(
                b2 + r * 128 + wave * 32 + nf2 * 16 + lhi * 4);
#pragma unroll
            for (int tf = 0; tf < 4; ++tf)
#pragma unroll
                for (int i = 0; i < 4; ++i)
                    facc[nf2][tf][i] += rw * tanh_fast(acc2[nf2][tf][i] + bv[i]);
        }
    }

    // ---- epilogue: group 0 -> dst = alpha*x + (1-alpha)*sum0;
    //                group 1 -> p1  = (1-alpha)*sum1  (combine adds) ----
    const float om = 1.0f - alpha;
    float* outb = (group == 0) ? (dst + (size_t)b * (T_ * D_))
                               : (p1 + (size_t)b * (T_ * D_));
#pragma unroll
    for (int tf = 0; tf < 4; ++tf) {
        const int t = t0 + tf * 16 + l16;
#pragma unroll
        for (int nf2 = 0; nf2 < 2; ++nf2) {
            const int c0 = wave * 32 + nf2 * 16 + lhi * 4;
            const size_t idx = (size_t)t * D_ + c0;
            f32x4 o;
            if (group == 0) {
                const f32x4 x = *reinterpret_cast<const f32x4*>(srcb + idx);
#pragma unroll
                for (int i = 0; i < 4; ++i) o[i] = alpha * x[i] + om * facc[nf2][tf][i];
            } else {
#pragma unroll
                for (int i = 0; i < 4; ++i) o[i] = om * facc[nf2][tf][i];
            }
            *reinterpret_cast<f32x4*>(outb + idx) = o;
        }
    }
}

// ---------------------------------------------------------------------------
// Combine: dst += p1 (guarded by n_evolve). f32x4 grid-stride-free.
// ---------------------------------------------------------------------------
__global__ __launch_bounds__(256) void combine_kernel(
    int step, const float* __restrict__ hdr,
    float* __restrict__ buf0, float* __restrict__ buf1,
    const float* __restrict__ p1)
{
    if (step >= (int)hdr[0]) return;
    float* dst = (step & 1) ? buf1 : buf0;
    const size_t i = ((size_t)blockIdx.x * 256 + threadIdx.x) * 4;
    f32x4 a = *reinterpret_cast<const f32x4*>(dst + i);
    const f32x4 c = *reinterpret_cast<const f32x4*>(p1 + i);
#pragma unroll
    for (int q = 0; q < 4; ++q) a[q] += c[q];
    *reinterpret_cast<f32x4*>(dst + i) = a;
}

// ---------------------------------------------------------------------------
// LayerNorm over D=128. One wave per row, 2 elems/lane.
// ---------------------------------------------------------------------------
__global__ __launch_bounds__(256) void ln_kernel(
    const float* __restrict__ buf0, const float* __restrict__ buf1,
    const float* __restrict__ hdr,
    const float* __restrict__ g, const float* __restrict__ bb,
    float* __restrict__ out)
{
    const int ne = (int)hdr[0];
    const float* src = ((ne - 1) & 1) ? buf1 : buf0;   // step s writes buf[s&1]
    const int row = blockIdx.x * 4 + (threadIdx.x >> 6);
    const int lane = threadIdx.x & 63;
    const size_t base = (size_t)row * D_;
    const int d = lane * 2;
    const float a = src[base + d];
    const float c = src[base + d + 1];
    float s = a + c;
    float q = a * a + c * c;
#pragma unroll
    for (int off = 32; off >= 1; off >>= 1) {
        s += __shfl_xor(s, off);
        q += __shfl_xor(q, off);
    }
    const float mean = s * (1.0f / 128.0f);
    float var = q * (1.0f / 128.0f) - mean * mean;
    var = fmaxf(var, 0.0f);
    const float rstd = rsqrtf(var + 1e-5f);
    out[base + d]     = (a - mean) * rstd * g[d] + bb[d];
    out[base + d + 1] = (c - mean) * rstd * g[d + 1] + bb[d + 1];
}

// ---------------------------------------------------------------------------
extern "C" void kernel_launch(void* const* d_in, const int* in_sizes, int n_in,
                              void* d_out, int out_size, void* d_ws, size_t ws_size,
                              hipStream_t stream)
{
    (void)in_sizes; (void)n_in; (void)out_size; (void)ws_size;
    const float* cells  = (const float*)d_in[0];
    const float* cst    = (const float*)d_in[1];
    const float* W1     = (const float*)d_in[2];
    const float* b1     = (const float*)d_in[3];
    const float* W2     = (const float*)d_in[4];
    const float* b2     = (const float*)d_in[5];
    const float* rW1    = (const float*)d_in[6];
    const float* rb1    = (const float*)d_in[7];
    const float* rW2    = (const float*)d_in[8];
    const float* rb2    = (const float*)d_in[9];
    const float* sW1    = (const float*)d_in[10];
    const float* sb1    = (const float*)d_in[11];
    const float* sW2    = (const float*)d_in[12];
    const float* sb2    = (const float*)d_in[13];
    const float* aW1    = (const float*)d_in[14];
    const float* ab1    = (const float*)d_in[15];
    const float* aW2    = (const float*)d_in[16];
    const float* ab2    = (const float*)d_in[17];
    const float* ln_g   = (const float*)d_in[18];
    const float* ln_b   = (const float*)d_in[19];
    float* out = (float*)d_out;

    char* ws = (char*)d_ws;
    float* hdr  = (float*)ws;                                        // 256 B
    float* buf0 = (float*)(ws + 256);                                // 16 MiB
    float* p1   = (float*)(ws + 256 + 16777216);                     // 16 MiB
    unsigned short* W1T = (unsigned short*)(ws + 256 + 2 * 16777216);  // 1.5 MiB
    unsigned short* W2T = W1T + (size_t)R_ * 256 * 384;                // 0.5 MiB
    float* buf1 = out;  // d_out doubles as ping-pong buffer (LN is in-place safe)

    hipLaunchKernelGGL(prep_weights, dim3(640), dim3(256), 0, stream, W1, W2, W1T, W2T);
    hipLaunchKernelGGL(selectors_kernel, dim3(1), dim3(64), 0, stream,
                       cst, rW1, rb1, rW2, rb2, sW1, sb1, sW2, sb2,
                       aW1, ab1, aW2, ab2, hdr);
    for (int s = 0; s < 8; ++s) {
        hipLaunchKernelGGL(evolve_step, dim3(1024), dim3(256), 0, stream,
                           s, cells, buf0, buf1, p1, W1T, W2T, b1, b2, hdr);
        hipLaunchKernelGGL(combine_kernel, dim3(4096), dim3(256), 0, stream,
                           s, hdr, buf0, buf1, p1);
    }
    hipLaunchKernelGGL(ln_kernel, dim3(8192), dim3(256), 0, stream,
                       buf0, buf1, hdr, ln_g, ln_b, out);
}

// Round 11
// 1259.829 us; speedup vs baseline: 1.2703x; 1.2703x over previous
//
#include <hip/hip_runtime.h>
#include <math.h>

#define T_ 4096
#define D_ 128
#define R_ 8

typedef float f32x4 __attribute__((ext_vector_type(4)));
typedef _Float16 f16x8 __attribute__((ext_vector_type(8)));
typedef unsigned short u16x8 __attribute__((ext_vector_type(8)));

__device__ __forceinline__ unsigned short f2h_bits(float f) {
    _Float16 h = (_Float16)f;
    return __builtin_bit_cast(unsigned short, h);
}

__device__ __forceinline__ unsigned long long pack4h(float a, float b, float c, float d) {
    unsigned int lo = __builtin_bit_cast(unsigned int, __builtin_amdgcn_cvt_pkrtz(a, b));
    unsigned int hi = __builtin_bit_cast(unsigned int, __builtin_amdgcn_cvt_pkrtz(c, d));
    return ((unsigned long long)hi << 32) | (unsigned long long)lo;
}

// tanh(x) = 1 - 2/(exp2(2*log2e*x)+1); large-|x| safe
__device__ __forceinline__ float tanh_fast(float x) {
    float e = __builtin_amdgcn_exp2f(x * 2.885390082f);
    float r = __builtin_amdgcn_rcpf(e + 1.0f);
    return fmaf(-2.0f, r, 1.0f);
}

// tanh-approx GELU: |err| ~1e-3 vs erf form (budget is 2%)
__device__ __forceinline__ float gelu_fast(float x) {
    float x2 = x * x;
    float u = x * fmaf(x2, 0.044715f, 1.0f);
    float e = __builtin_amdgcn_exp2f(u * -2.3022082f);
    return x * __builtin_amdgcn_rcpf(1.0f + e);
}

__device__ __forceinline__ float gelu_exact(float x) {
    return 0.5f * x * (1.0f + erff(x * 0.7071067811865475f));
}

// ---------------------------------------------------------------------------
// Selector MLPs (tiny): hdr[0]=n_evolve, hdr[1]=alpha, hdr[2..9]=rule_weights
// ---------------------------------------------------------------------------
__global__ void selectors_kernel(
    const float* __restrict__ c,
    const float* __restrict__ rW1, const float* __restrict__ rb1,
    const float* __restrict__ rW2, const float* __restrict__ rb2,
    const float* __restrict__ sW1, const float* __restrict__ sb1,
    const float* __restrict__ sW2, const float* __restrict__ sb2,
    const float* __restrict__ aW1, const float* __restrict__ ab1,
    const float* __restrict__ aW2, const float* __restrict__ ab2,
    float* __restrict__ hdr)
{
    __shared__ float cs[128];
    __shared__ float hb[64];
    __shared__ float lg[8];
    const int l = threadIdx.x;  // 64 threads
    cs[l] = c[l];
    cs[l + 64] = c[l + 64];
    __syncthreads();

    // rule selector: 128 -> 64 -> 8 -> softmax
    {
        float acc = rb1[l];
        for (int k = 0; k < 128; ++k) acc += cs[k] * rW1[k * 64 + l];
        hb[l] = gelu_exact(acc);
    }
    __syncthreads();
    if (l < 8) {
        float acc = rb2[l];
        for (int j = 0; j < 64; ++j) acc += hb[j] * rW2[j * 8 + l];
        lg[l] = acc;
    }
    __syncthreads();
    if (l == 0) {
        float mx = lg[0];
        for (int o = 1; o < 8; ++o) mx = fmaxf(mx, lg[o]);
        float e[8], se = 0.0f;
        for (int o = 0; o < 8; ++o) { e[o] = expf(lg[o] - mx); se += e[o]; }
        for (int o = 0; o < 8; ++o) hdr[2 + o] = e[o] / se;
    }
    __syncthreads();

    // steps selector: 128 -> 32 -> 7 -> softmax -> n_evolve
    if (l < 32) {
        float acc = sb1[l];
        for (int k = 0; k < 128; ++k) acc += cs[k] * sW1[k * 32 + l];
        hb[l] = gelu_exact(acc);
    }
    __syncthreads();
    if (l < 7) {
        float acc = sb2[l];
        for (int j = 0; j < 32; ++j) acc += hb[j] * sW2[j * 7 + l];
        lg[l] = acc;
    }
    __syncthreads();
    if (l == 0) {
        float mx = lg[0];
        for (int o = 1; o < 7; ++o) mx = fmaxf(mx, lg[o]);
        float e[7], se = 0.0f;
        for (int o = 0; o < 7; ++o) { e[o] = expf(lg[o] - mx); se += e[o]; }
        float n_soft = 0.0f;
        for (int o = 0; o < 7; ++o) n_soft += (e[o] / se) * (float)(2 + o);
        int ne = (int)floorf(n_soft + 0.5f);
        ne = ne < 2 ? 2 : (ne > 8 ? 8 : ne);
        hdr[0] = (float)ne;
    }
    __syncthreads();

    // alpha selector: 128 -> 32 -> 1 -> sigmoid
    if (l < 32) {
        float acc = ab1[l];
        for (int k = 0; k < 128; ++k) acc += cs[k] * aW1[k * 32 + l];
        hb[l] = gelu_exact(acc);
    }
    __syncthreads();
    if (l == 0) {
        float acc = ab2[0];
        for (int j = 0; j < 32; ++j) acc += hb[j] * aW2[j];
        hdr[1] = 0.1f + 0.8f / (1.0f + expf(-acc));
    }
}

// ---------------------------------------------------------------------------
// Weight prep, coalesced: lane -> n (contiguous source reads), each thread
// packs 8 consecutive k into one b128 store.
// ---------------------------------------------------------------------------
__global__ __launch_bounds__(256) void prep_weights(
    const float* __restrict__ W1, const float* __restrict__ W2,
    unsigned short* __restrict__ W1T, unsigned short* __restrict__ W2T)
{
    const int bx = blockIdx.x;
    if (bx < 384) {
        const int r = bx / 48;
        const int k0 = (bx % 48) * 8;
        const int n = threadIdx.x;          // 0..255
        u16x8 v;
#pragma unroll
        for (int j = 0; j < 8; ++j)
            v[j] = f2h_bits(W1[((size_t)r * 384 + k0 + j) * 256 + n]);
        *reinterpret_cast<u16x8*>(W1T + ((size_t)r * 256 + n) * 384 + k0) = v;
    } else {
        const int b2 = bx - 384;
        const int r = b2 / 32;
        const int k0 = (b2 % 32) * 8;
        const int n = threadIdx.x;
        if (n < 128) {
            u16x8 v;
#pragma unroll
            for (int j = 0; j < 8; ++j)
                v[j] = f2h_bits(W2[((size_t)r * 256 + k0 + j) * 128 + n]);
            *reinterpret_cast<u16x8*>(W2T + ((size_t)r * 128 + n) * 256 + k0) = v;
        }
    }
}

// ---------------------------------------------------------------------------
// One evolution step. Tile = 32 rows, 256 threads (4 waves), grid = 1024
// (4 blocks/CU by LDS 24.7 KB and VGPR ~105 -> 16 waves/CU, desynchronized).
// Full 8 rules per block (no split). Weights depth-1 double-buffered
// (covers L2 latency), LDS fragments single-buffered (keeps live set ~105
// total regs incl. AGPR accumulators -- the R6/R8/R9/R10 spill lesson).
// ---------------------------------------------------------------------------
__global__ __launch_bounds__(256, 4) void evolve_step(
    int step,
    const float* __restrict__ cells_in,
    float* __restrict__ buf0,
    float* __restrict__ buf1,
    const unsigned short* __restrict__ W1T,
    const unsigned short* __restrict__ W2T,
    const float* __restrict__ b1,
    const float* __restrict__ b2,
    const float* __restrict__ hdr)
{
    if (step >= (int)hdr[0]) return;
    const float* src = (step == 0) ? cells_in : ((step & 1) ? buf0 : buf1);
    float* dst = (step & 1) ? buf1 : buf0;
    const float alpha = hdr[1];

    // X tile: rows t0-1 .. t0+32 (34 x 128 fp16), XOR-swizzled  (8.7 KB)
    __shared__ __align__(16) unsigned short Xs[34 * 128];
    // H tile: 32 x 256 fp16, XOR-swizzled                       (16 KB)
    __shared__ __align__(16) unsigned short Hs[32 * 256];

    const int tid = threadIdx.x;
    const int blk = blockIdx.x;
    const int b = blk >> 7;
    const int t0 = (blk & 127) << 5;
    const float* srcb = src + (size_t)b * (T_ * D_);

    // ---- stage X tile (float4 load -> pack4h -> b64 swizzled store) ----
    {
        const int cr = (tid & 31) << 2;
        for (int j = (tid >> 5); j < 34; j += 8) {
            const int tg = (t0 + j - 1) & (T_ - 1);
            const f32x4 v = *reinterpret_cast<const f32x4*>(srcb + tg * D_ + cr);
            int byte = (j * 128 + cr) * 2;
            byte ^= (j & 7) << 4;
            *reinterpret_cast<unsigned long long*>(reinterpret_cast<char*>(Xs) + byte) =
                pack4h(v[0], v[1], v[2], v[3]);
        }
    }
    __syncthreads();

    const int wave = tid >> 6;
    const int lane = tid & 63;
    const int l16 = lane & 15;
    const int lhi = lane >> 4;
    const int kbase = lhi * 8;
    const char* Xsb = reinterpret_cast<const char*>(Xs);
    const char* Hsb = reinterpret_cast<const char*>(Hs);

    const f32x4 z4 = {0.0f, 0.0f, 0.0f, 0.0f};
    f32x4 facc[2][2];   // [nf2][tf]
#pragma unroll
    for (int a = 0; a < 2; ++a)
#pragma unroll
        for (int bq = 0; bq < 2; ++bq) facc[a][bq] = z4;

    for (int r = 0; r < R_; ++r) {
        // -------- GEMM1: H^T = W1^T X^T (wave owns H cols [64w, 64w+64)) ----
        f32x4 acc1[4][2];   // [nf][tf]
#pragma unroll
        for (int a = 0; a < 4; ++a)
#pragma unroll
            for (int bq = 0; bq < 2; ++bq) acc1[a][bq] = z4;

        const unsigned short* w1r = W1T + (size_t)r * (256 * 384);

        f16x8 wfr[2][4];
        // prologue: weights kk = 0 into buffer 0
#pragma unroll
        for (int nf = 0; nf < 4; ++nf)
            wfr[0][nf] = __builtin_bit_cast(f16x8, *reinterpret_cast<const u16x8*>(
                w1r + (size_t)(wave * 64 + nf * 16 + l16) * 384 + kbase));

#pragma unroll
        for (int kk = 0; kk < 12; ++kk) {
            const int cur = kk & 1;
            const int nxt = cur ^ 1;
            // prefetch next weight fragments (global, L2)
            if (kk < 11) {
                const int kgn = (kk + 1) * 32 + kbase;
#pragma unroll
                for (int nf = 0; nf < 4; ++nf)
                    wfr[nxt][nf] = __builtin_bit_cast(f16x8, *reinterpret_cast<const u16x8*>(
                        w1r + (size_t)(wave * 64 + nf * 16 + l16) * 384 + kgn));
            }
            // current X fragments from LDS (single-buffered)
            const int seg = kk >> 2;
            const int rowadd = (seg == 0) ? 1 : ((seg == 1) ? 0 : 2);
            const int kloc = ((kk & 3) * 32 + kbase) * 2;
            f16x8 xfr[2];
#pragma unroll
            for (int tf = 0; tf < 2; ++tf) {
                const int row = tf * 16 + l16 + rowadd;
                int byte = row * 256 + kloc;
                byte ^= (row & 7) << 4;
                xfr[tf] = __builtin_bit_cast(f16x8,
                    *reinterpret_cast<const u16x8*>(Xsb + byte));
            }
#pragma unroll
            for (int nf = 0; nf < 4; ++nf)
#pragma unroll
                for (int tf = 0; tf < 2; ++tf)
                    acc1[nf][tf] = __builtin_amdgcn_mfma_f32_16x16x32_f16(
                        wfr[cur][nf], xfr[tf], acc1[nf][tf], 0, 0, 0);
        }

        __syncthreads();   // previous rule's GEMM2 reads of Hs complete

        // bias + GELU -> Hs. Lane holds row t, cols n0..n0+3 -> b64 write
#pragma unroll
        for (int tf = 0; tf < 2; ++tf) {
            const int t = tf * 16 + l16;
            const int rowbyte = t * 512;
            const int swz = (t & 7) << 4;
#pragma unroll
            for (int nf = 0; nf < 4; ++nf) {
                const f32x4 bv = *reinterpret_cast<const f32x4*>(
                    b1 + r * 256 + wave * 64 + nf * 16 + lhi * 4);
                const f32x4 a = acc1[nf][tf];
                const float g0 = gelu_fast(a[0] + bv[0]);
                const float g1 = gelu_fast(a[1] + bv[1]);
                const float g2 = gelu_fast(a[2] + bv[2]);
                const float g3 = gelu_fast(a[3] + bv[3]);
                int byte = rowbyte + wave * 128 + nf * 32 + lhi * 8;
                byte ^= swz;
                *reinterpret_cast<unsigned long long*>(reinterpret_cast<char*>(Hs) + byte) =
                    pack4h(g0, g1, g2, g3);
            }
        }
        __syncthreads();

        // -------- GEMM2: O^T = W2^T H^T (wave owns O cols [32w, 32w+32)) ----
        f32x4 acc2[2][2];   // [nf2][tf]
#pragma unroll
        for (int a = 0; a < 2; ++a)
#pragma unroll
            for (int bq = 0; bq < 2; ++bq) acc2[a][bq] = z4;

        const unsigned short* w2r = W2T + (size_t)r * (128 * 256);

        f16x8 wfr2[2][2];
        // prologue k2 = 0
#pragma unroll
        for (int nf2 = 0; nf2 < 2; ++nf2)
            wfr2[0][nf2] = __builtin_bit_cast(f16x8, *reinterpret_cast<const u16x8*>(
                w2r + (size_t)(wave * 32 + nf2 * 16 + l16) * 256 + kbase));

#pragma unroll
        for (int k2 = 0; k2 < 8; ++k2) {
            const int cur = k2 & 1;
            const int nxt = cur ^ 1;
            if (k2 < 7) {
                const int kgn = (k2 + 1) * 32 + kbase;
#pragma unroll
                for (int nf2 = 0; nf2 < 2; ++nf2)
                    wfr2[nxt][nf2] = __builtin_bit_cast(f16x8, *reinterpret_cast<const u16x8*>(
                        w2r + (size_t)(wave * 32 + nf2 * 16 + l16) * 256 + kgn));
            }
            const int kg2 = (k2 * 32 + kbase) * 2;
            f16x8 hfr[2];
#pragma unroll
            for (int tf = 0; tf < 2; ++tf) {
                const int t = tf * 16 + l16;
                int byte = t * 512 + kg2;
                byte ^= (t & 7) << 4;
                hfr[tf] = __builtin_bit_cast(f16x8,
                    *reinterpret_cast<const u16x8*>(Hsb + byte));
            }
#pragma unroll
            for (int nf2 = 0; nf2 < 2; ++nf2)
#pragma unroll
                for (int tf = 0; tf < 2; ++tf)
                    acc2[nf2][tf] = __builtin_amdgcn_mfma_f32_16x16x32_f16(
                        wfr2[cur][nf2], hfr[tf], acc2[nf2][tf], 0, 0, 0);
        }

        const float rw = hdr[2 + r];
#pragma unroll
        for (int nf2 = 0; nf2 < 2; ++nf2) {
            const f32x4 bv = *reinterpret_cast<const f32x4*>(
                b2 + r * 128 + wave * 32 + nf2 * 16 + lhi * 4);
#pragma unroll
            for (int tf = 0; tf < 2; ++tf)
#pragma unroll
                for (int i = 0; i < 4; ++i)
                    facc[nf2][tf][i] += rw * tanh_fast(acc2[nf2][tf][i] + bv[i]);
        }
    }

    // ---- epilogue: cells = alpha*x + (1-alpha)*new, f32x4 in/out ----
    float* dstb = dst + (size_t)b * (T_ * D_);
    const float om = 1.0f - alpha;
#pragma unroll
    for (int tf = 0; tf < 2; ++tf) {
        const int t = t0 + tf * 16 + l16;
#pragma unroll
        for (int nf2 = 0; nf2 < 2; ++nf2) {
            const int c0 = wave * 32 + nf2 * 16 + lhi * 4;
            const size_t idx = (size_t)t * D_ + c0;
            const f32x4 x = *reinterpret_cast<const f32x4*>(srcb + idx);
            f32x4 o;
#pragma unroll
            for (int i = 0; i < 4; ++i) o[i] = alpha * x[i] + om * facc[nf2][tf][i];
            *reinterpret_cast<f32x4*>(dstb + idx) = o;
        }
    }
}

// ---------------------------------------------------------------------------
// LayerNorm over D=128. One wave per row, 2 elems/lane.
// ---------------------------------------------------------------------------
__global__ __launch_bounds__(256) void ln_kernel(
    const float* __restrict__ buf0, const float* __restrict__ buf1,
    const float* __restrict__ hdr,
    const float* __restrict__ g, const float* __restrict__ bb,
    float* __restrict__ out)
{
    const int ne = (int)hdr[0];
    const float* src = ((ne - 1) & 1) ? buf1 : buf0;   // step s writes buf[s&1]
    const int row = blockIdx.x * 4 + (threadIdx.x >> 6);
    const int lane = threadIdx.x & 63;
    const size_t base = (size_t)row * D_;
    const int d = lane * 2;
    const float a = src[base + d];
    const float c = src[base + d + 1];
    float s = a + c;
    float q = a * a + c * c;
#pragma unroll
    for (int off = 32; off >= 1; off >>= 1) {
        s += __shfl_xor(s, off);
        q += __shfl_xor(q, off);
    }
    const float mean = s * (1.0f / 128.0f);
    float var = q * (1.0f / 128.0f) - mean * mean;
    var = fmaxf(var, 0.0f);
    const float rstd = rsqrtf(var + 1e-5f);
    out[base + d]     = (a - mean) * rstd * g[d] + bb[d];
    out[base + d + 1] = (c - mean) * rstd * g[d + 1] + bb[d + 1];
}

// ---------------------------------------------------------------------------
extern "C" void kernel_launch(void* const* d_in, const int* in_sizes, int n_in,
                              void* d_out, int out_size, void* d_ws, size_t ws_size,
                              hipStream_t stream)
{
    (void)in_sizes; (void)n_in; (void)out_size; (void)ws_size;
    const float* cells  = (const float*)d_in[0];
    const float* cst    = (const float*)d_in[1];
    const float* W1     = (const float*)d_in[2];
    const float* b1     = (const float*)d_in[3];
    const float* W2     = (const float*)d_in[4];
    const float* b2     = (const float*)d_in[5];
    const float* rW1    = (const float*)d_in[6];
    const float* rb1    = (const float*)d_in[7];
    const float* rW2    = (const float*)d_in[8];
    const float* rb2    = (const float*)d_in[9];
    const float* sW1    = (const float*)d_in[10];
    const float* sb1    = (const float*)d_in[11];
    const float* sW2    = (const float*)d_in[12];
    const float* sb2    = (const float*)d_in[13];
    const float* aW1    = (const float*)d_in[14];
    const float* ab1    = (const float*)d_in[15];
    const float* aW2    = (const float*)d_in[16];
    const float* ab2    = (const float*)d_in[17];
    const float* ln_g   = (const float*)d_in[18];
    const float* ln_b   = (const float*)d_in[19];
    float* out = (float*)d_out;

    char* ws = (char*)d_ws;
    float* hdr  = (float*)ws;                                      // 256 B
    float* buf0 = (float*)(ws + 256);                              // 16 MiB
    unsigned short* W1T = (unsigned short*)(ws + 256 + 16777216);  // 1.5 MiB
    unsigned short* W2T = W1T + (size_t)R_ * 256 * 384;            // 0.5 MiB
    float* buf1 = out;  // d_out doubles as ping-pong buffer (LN is in-place safe)

    hipLaunchKernelGGL(prep_weights, dim3(640), dim3(256), 0, stream, W1, W2, W1T, W2T);
    hipLaunchKernelGGL(selectors_kernel, dim3(1), dim3(64), 0, stream,
                       cst, rW1, rb1, rW2, rb2, sW1, sb1, sW2, sb2,
                       aW1, ab1, aW2, ab2, hdr);
    for (int s = 0; s < 8; ++s) {
        hipLaunchKernelGGL(evolve_step, dim3(1024), dim3(256), 0, stream,
                           s, cells, buf0, buf1, W1T, W2T, b1, b2, hdr);
    }
    hipLaunchKernelGGL(ln_kernel, dim3(8192), dim3(256), 0, stream,
                       buf0, buf1, hdr, ln_g, ln_b, out);
}

// Round 12
// 851.881 us; speedup vs baseline: 1.8786x; 1.4789x over previous
//
#include <hip/hip_runtime.h>
#include <math.h>

#define T_ 4096
#define D_ 128
#define R_ 8

// Barrier that drains ONLY LDS ops (lgkmcnt) -- global prefetches (vmcnt)
// stay in flight across it. __syncthreads() would emit s_waitcnt vmcnt(0)
// and cold-restart the weight pipeline at every rule boundary (T4 lesson).
#define LDS_BARRIER() asm volatile("s_waitcnt lgkmcnt(0)\n\ts_barrier" ::: "memory")

typedef float f32x4 __attribute__((ext_vector_type(4)));
typedef _Float16 f16x8 __attribute__((ext_vector_type(8)));
typedef unsigned short u16x8 __attribute__((ext_vector_type(8)));

__device__ __forceinline__ unsigned short f2h_bits(float f) {
    _Float16 h = (_Float16)f;
    return __builtin_bit_cast(unsigned short, h);
}

__device__ __forceinline__ unsigned long long pack4h(float a, float b, float c, float d) {
    unsigned int lo = __builtin_bit_cast(unsigned int, __builtin_amdgcn_cvt_pkrtz(a, b));
    unsigned int hi = __builtin_bit_cast(unsigned int, __builtin_amdgcn_cvt_pkrtz(c, d));
    return ((unsigned long long)hi << 32) | (unsigned long long)lo;
}

// tanh(x) = 1 - 2/(exp2(2*log2e*x)+1); large-|x| safe
__device__ __forceinline__ float tanh_fast(float x) {
    float e = __builtin_amdgcn_exp2f(x * 2.885390082f);
    float r = __builtin_amdgcn_rcpf(e + 1.0f);
    return fmaf(-2.0f, r, 1.0f);
}

// tanh-approx GELU: |err| ~1e-3 vs erf form (budget is 2%)
__device__ __forceinline__ float gelu_fast(float x) {
    float x2 = x * x;
    float u = x * fmaf(x2, 0.044715f, 1.0f);
    float e = __builtin_amdgcn_exp2f(u * -2.3022082f);
    return x * __builtin_amdgcn_rcpf(1.0f + e);
}

__device__ __forceinline__ float gelu_exact(float x) {
    return 0.5f * x * (1.0f + erff(x * 0.7071067811865475f));
}

// ---------------------------------------------------------------------------
// Selector MLPs (tiny): hdr[0]=n_evolve, hdr[1]=alpha, hdr[2..9]=rule_weights
// ---------------------------------------------------------------------------
__global__ void selectors_kernel(
    const float* __restrict__ c,
    const float* __restrict__ rW1, const float* __restrict__ rb1,
    const float* __restrict__ rW2, const float* __restrict__ rb2,
    const float* __restrict__ sW1, const float* __restrict__ sb1,
    const float* __restrict__ sW2, const float* __restrict__ sb2,
    const float* __restrict__ aW1, const float* __restrict__ ab1,
    const float* __restrict__ aW2, const float* __restrict__ ab2,
    float* __restrict__ hdr)
{
    __shared__ float cs[128];
    __shared__ float hb[64];
    __shared__ float lg[8];
    const int l = threadIdx.x;  // 64 threads
    cs[l] = c[l];
    cs[l + 64] = c[l + 64];
    __syncthreads();

    // rule selector: 128 -> 64 -> 8 -> softmax
    {
        float acc = rb1[l];
        for (int k = 0; k < 128; ++k) acc += cs[k] * rW1[k * 64 + l];
        hb[l] = gelu_exact(acc);
    }
    __syncthreads();
    if (l < 8) {
        float acc = rb2[l];
        for (int j = 0; j < 64; ++j) acc += hb[j] * rW2[j * 8 + l];
        lg[l] = acc;
    }
    __syncthreads();
    if (l == 0) {
        float mx = lg[0];
        for (int o = 1; o < 8; ++o) mx = fmaxf(mx, lg[o]);
        float e[8], se = 0.0f;
        for (int o = 0; o < 8; ++o) { e[o] = expf(lg[o] - mx); se += e[o]; }
        for (int o = 0; o < 8; ++o) hdr[2 + o] = e[o] / se;
    }
    __syncthreads();

    // steps selector: 128 -> 32 -> 7 -> softmax -> n_evolve
    if (l < 32) {
        float acc = sb1[l];
        for (int k = 0; k < 128; ++k) acc += cs[k] * sW1[k * 32 + l];
        hb[l] = gelu_exact(acc);
    }
    __syncthreads();
    if (l < 7) {
        float acc = sb2[l];
        for (int j = 0; j < 32; ++j) acc += hb[j] * sW2[j * 7 + l];
        lg[l] = acc;
    }
    __syncthreads();
    if (l == 0) {
        float mx = lg[0];
        for (int o = 1; o < 7; ++o) mx = fmaxf(mx, lg[o]);
        float e[7], se = 0.0f;
        for (int o = 0; o < 7; ++o) { e[o] = expf(lg[o] - mx); se += e[o]; }
        float n_soft = 0.0f;
        for (int o = 0; o < 7; ++o) n_soft += (e[o] / se) * (float)(2 + o);
        int ne = (int)floorf(n_soft + 0.5f);
        ne = ne < 2 ? 2 : (ne > 8 ? 8 : ne);
        hdr[0] = (float)ne;
    }
    __syncthreads();

    // alpha selector: 128 -> 32 -> 1 -> sigmoid
    if (l < 32) {
        float acc = ab1[l];
        for (int k = 0; k < 128; ++k) acc += cs[k] * aW1[k * 32 + l];
        hb[l] = gelu_exact(acc);
    }
    __syncthreads();
    if (l == 0) {
        float acc = ab2[0];
        for (int j = 0; j < 32; ++j) acc += hb[j] * aW2[j];
        hdr[1] = 0.1f + 0.8f / (1.0f + expf(-acc));
    }
}

// ---------------------------------------------------------------------------
// Weight prep, coalesced: lane -> n (contiguous source reads), each thread
// packs 8 consecutive k into one b128 store.
// ---------------------------------------------------------------------------
__global__ __launch_bounds__(256) void prep_weights(
    const float* __restrict__ W1, const float* __restrict__ W2,
    unsigned short* __restrict__ W1T, unsigned short* __restrict__ W2T)
{
    const int bx = blockIdx.x;
    if (bx < 384) {
        const int r = bx / 48;
        const int k0 = (bx % 48) * 8;
        const int n = threadIdx.x;          // 0..255
        u16x8 v;
#pragma unroll
        for (int j = 0; j < 8; ++j)
            v[j] = f2h_bits(W1[((size_t)r * 384 + k0 + j) * 256 + n]);
        *reinterpret_cast<u16x8*>(W1T + ((size_t)r * 256 + n) * 384 + k0) = v;
    } else {
        const int b2 = bx - 384;
        const int r = b2 / 32;
        const int k0 = (b2 % 32) * 8;
        const int n = threadIdx.x;
        if (n < 128) {
            u16x8 v;
#pragma unroll
            for (int j = 0; j < 8; ++j)
                v[j] = f2h_bits(W2[((size_t)r * 256 + k0 + j) * 128 + n]);
            *reinterpret_cast<u16x8*>(W2T + ((size_t)r * 128 + n) * 256 + k0) = v;
        }
    }
}

// ---------------------------------------------------------------------------
// One evolution step. R4 structure (tile = 64 rows, 256 threads / 4 waves,
// grid = 512, full depth-1 double-buffered prefetch, VGPR 128 no-spill,
// 173 us/step) with ONE change: in-loop barriers are LDS-only (lgkmcnt),
// so weight prefetches survive the 16 barriers/step instead of being
// vmcnt(0)-drained at each (the m97 ~20% stall, x16 here).
// ---------------------------------------------------------------------------
__global__ __launch_bounds__(256, 2) void evolve_step(
    int step,
    const float* __restrict__ cells_in,
    float* __restrict__ buf0,
    float* __restrict__ buf1,
    const unsigned short* __restrict__ W1T,
    const unsigned short* __restrict__ W2T,
    const float* __restrict__ b1,
    const float* __restrict__ b2,
    const float* __restrict__ hdr)
{
    if (step >= (int)hdr[0]) return;
    const float* src = (step == 0) ? cells_in : ((step & 1) ? buf0 : buf1);
    float* dst = (step & 1) ? buf1 : buf0;
    const float alpha = hdr[1];

    // X tile: rows t0-1 .. t0+64 (66 x 128 fp16), XOR-swizzled
    __shared__ __align__(16) unsigned short Xs[66 * 128];
    // H tile: 64 x 256 fp16, XOR-swizzled
    __shared__ __align__(16) unsigned short Hs[64 * 256];

    const int tid = threadIdx.x;
    const int blk = blockIdx.x;
    const int b = blk >> 6;
    const int t0 = (blk & 63) << 6;
    const float* srcb = src + (size_t)b * (T_ * D_);

    // ---- stage X tile (float4 load -> pack4h -> b64 swizzled store) ----
    {
        const int cr = (tid & 31) << 2;
        for (int j = (tid >> 5); j < 66; j += 8) {
            const int tg = (t0 + j - 1) & (T_ - 1);
            const f32x4 v = *reinterpret_cast<const f32x4*>(srcb + tg * D_ + cr);
            int byte = (j * 128 + cr) * 2;
            byte ^= (j & 7) << 4;
            *reinterpret_cast<unsigned long long*>(reinterpret_cast<char*>(Xs) + byte) =
                pack4h(v[0], v[1], v[2], v[3]);
        }
    }
    __syncthreads();   // full barrier once: staging loads must land

    const int wave = tid >> 6;
    const int lane = tid & 63;
    const int l16 = lane & 15;
    const int lhi = lane >> 4;
    const int kbase = lhi * 8;
    const char* Xsb = reinterpret_cast<const char*>(Xs);
    const char* Hsb = reinterpret_cast<const char*>(Hs);

    const f32x4 z4 = {0.0f, 0.0f, 0.0f, 0.0f};
    f32x4 facc[2][4];   // [nf2][tf]
#pragma unroll
    for (int a = 0; a < 2; ++a)
#pragma unroll
        for (int bq = 0; bq < 4; ++bq) facc[a][bq] = z4;

    for (int r = 0; r < R_; ++r) {
        // -------- GEMM1: H^T = W1^T X^T (wave owns H cols [64w, 64w+64)) ----
        f32x4 acc1[4][4];   // [nf][tf]
#pragma unroll
        for (int a = 0; a < 4; ++a)
#pragma unroll
            for (int bq = 0; bq < 4; ++bq) acc1[a][bq] = z4;

        const unsigned short* w1r = W1T + (size_t)r * (256 * 384);

        f16x8 wfr[2][4], xfr[2][4];
        // prologue: kk = 0 into buffer 0  (seg 0 -> rowadd 1)
#pragma unroll
        for (int nf = 0; nf < 4; ++nf)
            wfr[0][nf] = __builtin_bit_cast(f16x8, *reinterpret_cast<const u16x8*>(
                w1r + (size_t)(wave * 64 + nf * 16 + l16) * 384 + kbase));
#pragma unroll
        for (int tf = 0; tf < 4; ++tf) {
            const int row = tf * 16 + l16 + 1;
            int byte = row * 256 + kbase * 2;
            byte ^= (row & 7) << 4;
            xfr[0][tf] = __builtin_bit_cast(f16x8, *reinterpret_cast<const u16x8*>(Xsb + byte));
        }

#pragma unroll
        for (int kk = 0; kk < 12; ++kk) {
            const int cur = kk & 1;
            const int nxt = cur ^ 1;
            if (kk < 11) {
                const int kn = kk + 1;
                const int segn = kn >> 2;
                const int rowaddn = (segn == 0) ? 1 : ((segn == 1) ? 0 : 2);
                const int klocn = ((kn & 3) * 32 + kbase) * 2;
                const int kgn = kn * 32 + kbase;
#pragma unroll
                for (int nf = 0; nf < 4; ++nf)
                    wfr[nxt][nf] = __builtin_bit_cast(f16x8, *reinterpret_cast<const u16x8*>(
                        w1r + (size_t)(wave * 64 + nf * 16 + l16) * 384 + kgn));
#pragma unroll
                for (int tf = 0; tf < 4; ++tf) {
                    const int row = tf * 16 + l16 + rowaddn;
                    int byte = row * 256 + klocn;
                    byte ^= (row & 7) << 4;
                    xfr[nxt][tf] = __builtin_bit_cast(f16x8,
                        *reinterpret_cast<const u16x8*>(Xsb + byte));
                }
            }
#pragma unroll
            for (int nf = 0; nf < 4; ++nf)
#pragma unroll
                for (int tf = 0; tf < 4; ++tf)
                    acc1[nf][tf] = __builtin_amdgcn_mfma_f32_16x16x32_f16(
                        wfr[cur][nf], xfr[cur][tf], acc1[nf][tf], 0, 0, 0);
        }

        LDS_BARRIER();   // previous rule's GEMM2 reads of Hs complete (LDS-only)

        // bias + GELU -> Hs. Lane holds row t, cols n0..n0+3 -> b64 write
#pragma unroll
        for (int tf = 0; tf < 4; ++tf) {
            const int t = tf * 16 + l16;
            const int rowbyte = t * 512;
            const int swz = (t & 7) << 4;
#pragma unroll
            for (int nf = 0; nf < 4; ++nf) {
                const f32x4 bv = *reinterpret_cast<const f32x4*>(
                    b1 + r * 256 + wave * 64 + nf * 16 + lhi * 4);
                const f32x4 a = acc1[nf][tf];
                const float g0 = gelu_fast(a[0] + bv[0]);
                const float g1 = gelu_fast(a[1] + bv[1]);
                const float g2 = gelu_fast(a[2] + bv[2]);
                const float g3 = gelu_fast(a[3] + bv[3]);
                int byte = rowbyte + wave * 128 + nf * 32 + lhi * 8;
                byte ^= swz;
                *reinterpret_cast<unsigned long long*>(reinterpret_cast<char*>(Hs) + byte) =
                    pack4h(g0, g1, g2, g3);
            }
        }
        LDS_BARRIER();   // Hs writes visible to all waves (LDS-only)

        // -------- GEMM2: O^T = W2^T H^T (wave owns O cols [32w, 32w+32)) ----
        f32x4 acc2[2][4];   // [nf2][tf]
#pragma unroll
        for (int a = 0; a < 2; ++a)
#pragma unroll
            for (int bq = 0; bq < 4; ++bq) acc2[a][bq] = z4;

        const unsigned short* w2r = W2T + (size_t)r * (128 * 256);

        f16x8 hfr[2][4], wfr2[2][2];
        // prologue k2 = 0
#pragma unroll
        for (int nf2 = 0; nf2 < 2; ++nf2)
            wfr2[0][nf2] = __builtin_bit_cast(f16x8, *reinterpret_cast<const u16x8*>(
                w2r + (size_t)(wave * 32 + nf2 * 16 + l16) * 256 + kbase));
#pragma unroll
        for (int tf = 0; tf < 4; ++tf) {
            const int t = tf * 16 + l16;
            int byte = t * 512 + kbase * 2;
            byte ^= (t & 7) << 4;
            hfr[0][tf] = __builtin_bit_cast(f16x8, *reinterpret_cast<const u16x8*>(Hsb + byte));
        }

#pragma unroll
        for (int k2 = 0; k2 < 8; ++k2) {
            const int cur = k2 & 1;
            const int nxt = cur ^ 1;
            if (k2 < 7) {
                const int kgn = (k2 + 1) * 32 + kbase;
#pragma unroll
                for (int nf2 = 0; nf2 < 2; ++nf2)
                    wfr2[nxt][nf2] = __builtin_bit_cast(f16x8, *reinterpret_cast<const u16x8*>(
                        w2r + (size_t)(wave * 32 + nf2 * 16 + l16) * 256 + kgn));
#pragma unroll
                for (int tf = 0; tf < 4; ++tf) {
                    const int t = tf * 16 + l16;
                    int byte = t * 512 + kgn * 2;
                    byte ^= (t & 7) << 4;
                    hfr[nxt][tf] = __builtin_bit_cast(f16x8,
                        *reinterpret_cast<const u16x8*>(Hsb + byte));
                }
            }
#pragma unroll
            for (int nf2 = 0; nf2 < 2; ++nf2)
#pragma unroll
                for (int tf = 0; tf < 4; ++tf)
                    acc2[nf2][tf] = __builtin_amdgcn_mfma_f32_16x16x32_f16(
                        wfr2[cur][nf2], hfr[cur][tf], acc2[nf2][tf], 0, 0, 0);
        }

        const float rw = hdr[2 + r];
#pragma unroll
        for (int nf2 = 0; nf2 < 2; ++nf2) {
            const f32x4 bv = *reinterpret_cast<const f32x4*>(
                b2 + r * 128 + wave * 32 + nf2 * 16 + lhi * 4);
#pragma unroll
            for (int tf = 0; tf < 4; ++tf)
#pragma unroll
                for (int i = 0; i < 4; ++i)
                    facc[nf2][tf][i] += rw * tanh_fast(acc2[nf2][tf][i] + bv[i]);
        }
    }

    // ---- epilogue: cells = alpha*x + (1-alpha)*new, f32x4 in/out ----
    float* dstb = dst + (size_t)b * (T_ * D_);
    const float om = 1.0f - alpha;
#pragma unroll
    for (int tf = 0; tf < 4; ++tf) {
        const int t = t0 + tf * 16 + l16;
#pragma unroll
        for (int nf2 = 0; nf2 < 2; ++nf2) {
            const int c0 = wave * 32 + nf2 * 16 + lhi * 4;
            const size_t idx = (size_t)t * D_ + c0;
            const f32x4 x = *reinterpret_cast<const f32x4*>(srcb + idx);
            f32x4 o;
#pragma unroll
            for (int i = 0; i < 4; ++i) o[i] = alpha * x[i] + om * facc[nf2][tf][i];
            *reinterpret_cast<f32x4*>(dstb + idx) = o;
        }
    }
}

// ---------------------------------------------------------------------------
// LayerNorm over D=128. One wave per row, 2 elems/lane.
// ---------------------------------------------------------------------------
__global__ __launch_bounds__(256) void ln_kernel(
    const float* __restrict__ buf0, const float* __restrict__ buf1,
    const float* __restrict__ hdr,
    const float* __restrict__ g, const float* __restrict__ bb,
    float* __restrict__ out)
{
    const int ne = (int)hdr[0];
    const float* src = ((ne - 1) & 1) ? buf1 : buf0;   // step s writes buf[s&1]
    const int row = blockIdx.x * 4 + (threadIdx.x >> 6);
    const int lane = threadIdx.x & 63;
    const size_t base = (size_t)row * D_;
    const int d = lane * 2;
    const float a = src[base + d];
    const float c = src[base + d + 1];
    float s = a + c;
    float q = a * a + c * c;
#pragma unroll
    for (int off = 32; off >= 1; off >>= 1) {
        s += __shfl_xor(s, off);
        q += __shfl_xor(q, off);
    }
    const float mean = s * (1.0f / 128.0f);
    float var = q * (1.0f / 128.0f) - mean * mean;
    var = fmaxf(var, 0.0f);
    const float rstd = rsqrtf(var + 1e-5f);
    out[base + d]     = (a - mean) * rstd * g[d] + bb[d];
    out[base + d + 1] = (c - mean) * rstd * g[d + 1] + bb[d + 1];
}

// ---------------------------------------------------------------------------
extern "C" void kernel_launch(void* const* d_in, const int* in_sizes, int n_in,
                              void* d_out, int out_size, void* d_ws, size_t ws_size,
                              hipStream_t stream)
{
    (void)in_sizes; (void)n_in; (void)out_size; (void)ws_size;
    const float* cells  = (const float*)d_in[0];
    const float* cst    = (const float*)d_in[1];
    const float* W1     = (const float*)d_in[2];
    const float* b1     = (const float*)d_in[3];
    const float* W2     = (const float*)d_in[4];
    const float* b2     = (const float*)d_in[5];
    const float* rW1    = (const float*)d_in[6];
    const float* rb1    = (const float*)d_in[7];
    const float* rW2    = (const float*)d_in[8];
    const float* rb2    = (const float*)d_in[9];
    const float* sW1    = (const float*)d_in[10];
    const float* sb1    = (const float*)d_in[11];
    const float* sW2    = (const float*)d_in[12];
    const float* sb2    = (const float*)d_in[13];
    const float* aW1    = (const float*)d_in[14];
    const float* ab1    = (const float*)d_in[15];
    const float* aW2    = (const float*)d_in[16];
    const float* ab2    = (const float*)d_in[17];
    const float* ln_g   = (const float*)d_in[18];
    const float* ln_b   = (const float*)d_in[19];
    float* out = (float*)d_out;

    char* ws = (char*)d_ws;
    float* hdr  = (float*)ws;                                      // 256 B
    float* buf0 = (float*)(ws + 256);                              // 16 MiB
    unsigned short* W1T = (unsigned short*)(ws + 256 + 16777216);  // 1.5 MiB
    unsigned short* W2T = W1T + (size_t)R_ * 256 * 384;            // 0.5 MiB
    float* buf1 = out;  // d_out doubles as ping-pong buffer (LN is in-place safe)

    hipLaunchKernelGGL(prep_weights, dim3(640), dim3(256), 0, stream, W1, W2, W1T, W2T);
    hipLaunchKernelGGL(selectors_kernel, dim3(1), dim3(64), 0, stream,
                       cst, rW1, rb1, rW2, rb2, sW1, sb1, sW2, sb2,
                       aW1, ab1, aW2, ab2, hdr);
    for (int s = 0; s < 8; ++s) {
        hipLaunchKernelGGL(evolve_step, dim3(512), dim3(256), 0, stream,
                           s, cells, buf0, buf1, W1T, W2T, b1, b2, hdr);
    }
    hipLaunchKernelGGL(ln_kernel, dim3(8192), dim3(256), 0, stream,
                       buf0, buf1, hdr, ln_g, ln_b, out);
}

// Round 13
// 791.101 us; speedup vs baseline: 2.0229x; 1.0768x over previous
//
#include <hip/hip_runtime.h>
#include <math.h>

#define T_ 4096
#define D_ 128
#define R_ 8

// LDS-only barrier: drains lgkmcnt, leaves global prefetches (vmcnt) in flight.
#define LDS_BARRIER() asm volatile("s_waitcnt lgkmcnt(0)\n\ts_barrier" ::: "memory")

typedef float f32x4 __attribute__((ext_vector_type(4)));
typedef _Float16 f16x8 __attribute__((ext_vector_type(8)));
typedef unsigned short u16x8 __attribute__((ext_vector_type(8)));

__device__ __forceinline__ unsigned short f2h_bits(float f) {
    _Float16 h = (_Float16)f;
    return __builtin_bit_cast(unsigned short, h);
}

__device__ __forceinline__ unsigned long long pack4h(float a, float b, float c, float d) {
    unsigned int lo = __builtin_bit_cast(unsigned int, __builtin_amdgcn_cvt_pkrtz(a, b));
    unsigned int hi = __builtin_bit_cast(unsigned int, __builtin_amdgcn_cvt_pkrtz(c, d));
    return ((unsigned long long)hi << 32) | (unsigned long long)lo;
}

// tanh(x) = 1 - 2/(exp2(2*log2e*x)+1); large-|x| safe
__device__ __forceinline__ float tanh_fast(float x) {
    float e = __builtin_amdgcn_exp2f(x * 2.885390082f);
    float r = __builtin_amdgcn_rcpf(e + 1.0f);
    return fmaf(-2.0f, r, 1.0f);
}

// tanh-approx GELU: |err| ~1e-3 vs erf form (budget is 2%)
__device__ __forceinline__ float gelu_fast(float x) {
    float x2 = x * x;
    float u = x * fmaf(x2, 0.044715f, 1.0f);
    float e = __builtin_amdgcn_exp2f(u * -2.3022082f);
    return x * __builtin_amdgcn_rcpf(1.0f + e);
}

__device__ __forceinline__ float gelu_exact(float x) {
    return 0.5f * x * (1.0f + erff(x * 0.7071067811865475f));
}

// ---------------------------------------------------------------------------
// Selector MLPs (tiny): hdr[0]=n_evolve, hdr[1]=alpha, hdr[2..9]=rule_weights
// ---------------------------------------------------------------------------
__global__ void selectors_kernel(
    const float* __restrict__ c,
    const float* __restrict__ rW1, const float* __restrict__ rb1,
    const float* __restrict__ rW2, const float* __restrict__ rb2,
    const float* __restrict__ sW1, const float* __restrict__ sb1,
    const float* __restrict__ sW2, const float* __restrict__ sb2,
    const float* __restrict__ aW1, const float* __restrict__ ab1,
    const float* __restrict__ aW2, const float* __restrict__ ab2,
    float* __restrict__ hdr)
{
    __shared__ float cs[128];
    __shared__ float hb[64];
    __shared__ float lg[8];
    const int l = threadIdx.x;  // 64 threads
    cs[l] = c[l];
    cs[l + 64] = c[l + 64];
    __syncthreads();

    // rule selector: 128 -> 64 -> 8 -> softmax
    {
        float acc = rb1[l];
        for (int k = 0; k < 128; ++k) acc += cs[k] * rW1[k * 64 + l];
        hb[l] = gelu_exact(acc);
    }
    __syncthreads();
    if (l < 8) {
        float acc = rb2[l];
        for (int j = 0; j < 64; ++j) acc += hb[j] * rW2[j * 8 + l];
        lg[l] = acc;
    }
    __syncthreads();
    if (l == 0) {
        float mx = lg[0];
        for (int o = 1; o < 8; ++o) mx = fmaxf(mx, lg[o]);
        float e[8], se = 0.0f;
        for (int o = 0; o < 8; ++o) { e[o] = expf(lg[o] - mx); se += e[o]; }
        for (int o = 0; o < 8; ++o) hdr[2 + o] = e[o] / se;
    }
    __syncthreads();

    // steps selector: 128 -> 32 -> 7 -> softmax -> n_evolve
    if (l < 32) {
        float acc = sb1[l];
        for (int k = 0; k < 128; ++k) acc += cs[k] * sW1[k * 32 + l];
        hb[l] = gelu_exact(acc);
    }
    __syncthreads();
    if (l < 7) {
        float acc = sb2[l];
        for (int j = 0; j < 32; ++j) acc += hb[j] * sW2[j * 7 + l];
        lg[l] = acc;
    }
    __syncthreads();
    if (l == 0) {
        float mx = lg[0];
        for (int o = 1; o < 7; ++o) mx = fmaxf(mx, lg[o]);
        float e[7], se = 0.0f;
        for (int o = 0; o < 7; ++o) { e[o] = expf(lg[o] - mx); se += e[o]; }
        float n_soft = 0.0f;
        for (int o = 0; o < 7; ++o) n_soft += (e[o] / se) * (float)(2 + o);
        int ne = (int)floorf(n_soft + 0.5f);
        ne = ne < 2 ? 2 : (ne > 8 ? 8 : ne);
        hdr[0] = (float)ne;
    }
    __syncthreads();

    // alpha selector: 128 -> 32 -> 1 -> sigmoid
    if (l < 32) {
        float acc = ab1[l];
        for (int k = 0; k < 128; ++k) acc += cs[k] * aW1[k * 32 + l];
        hb[l] = gelu_exact(acc);
    }
    __syncthreads();
    if (l == 0) {
        float acc = ab2[0];
        for (int j = 0; j < 32; ++j) acc += hb[j] * aW2[j];
        hdr[1] = 0.1f + 0.8f / (1.0f + expf(-acc));
    }
}

// ---------------------------------------------------------------------------
// Weight prep, coalesced: lane -> n (contiguous source reads), each thread
// packs 8 consecutive k into one b128 store.
// ---------------------------------------------------------------------------
__global__ __launch_bounds__(256) void prep_weights(
    const float* __restrict__ W1, const float* __restrict__ W2,
    unsigned short* __restrict__ W1T, unsigned short* __restrict__ W2T)
{
    const int bx = blockIdx.x;
    if (bx < 384) {
        const int r = bx / 48;
        const int k0 = (bx % 48) * 8;
        const int n = threadIdx.x;          // 0..255
        u16x8 v;
#pragma unroll
        for (int j = 0; j < 8; ++j)
            v[j] = f2h_bits(W1[((size_t)r * 384 + k0 + j) * 256 + n]);
        *reinterpret_cast<u16x8*>(W1T + ((size_t)r * 256 + n) * 384 + k0) = v;
    } else {
        const int b2 = bx - 384;
        const int r = b2 / 32;
        const int k0 = (b2 % 32) * 8;
        const int n = threadIdx.x;
        if (n < 128) {
            u16x8 v;
#pragma unroll
            for (int j = 0; j < 8; ++j)
                v[j] = f2h_bits(W2[((size_t)r * 256 + k0 + j) * 128 + n]);
            *reinterpret_cast<u16x8*>(W2T + ((size_t)r * 128 + n) * 256 + k0) = v;
        }
    }
}

// ---------------------------------------------------------------------------
// One evolution step, RULE-PIPELINED. Tile = 64 rows, 512 threads (8 waves),
// grid = 512 (1 block/CU, 2 sequential rounds). Hs double-buffered: iteration
// r computes GEMM1(r)->GELU->Hs[r&1] AND GEMM2(r-1) from Hs[(r-1)&1] inside
// ONE LDS-only barrier interval -> 9 barriers/step instead of 16, ~128 MFMA
// per interval, GELU/tanh VALU overlaps co-wave MFMA. Per-wave register live
// set ~116 (acc1 32 + xfr dbuf 32 + wfr 16 + facc 16 + misc) -- no spill.
// ---------------------------------------------------------------------------
__global__ __launch_bounds__(512, 2) void evolve_step(
    int step,
    const float* __restrict__ cells_in,
    float* __restrict__ buf0,
    float* __restrict__ buf1,
    const unsigned short* __restrict__ W1T,
    const unsigned short* __restrict__ W2T,
    const float* __restrict__ b1,
    const float* __restrict__ b2,
    const float* __restrict__ hdr)
{
    if (step >= (int)hdr[0]) return;
    const float* src = (step == 0) ? cells_in : ((step & 1) ? buf0 : buf1);
    float* dst = (step & 1) ? buf1 : buf0;
    const float alpha = hdr[1];

    // X tile: rows t0-1 .. t0+64 (66 x 128 fp16), XOR-swizzled  (16.9 KB)
    __shared__ __align__(16) unsigned short Xs[66 * 128];
    // H tiles, double-buffered: 2 x 64 x 256 fp16, XOR-swizzled (64 KB)
    __shared__ __align__(16) unsigned short Hs[2 * 64 * 256];

    const int tid = threadIdx.x;
    const int blk = blockIdx.x;
    const int b = blk >> 6;
    const int t0 = (blk & 63) << 6;
    const float* srcb = src + (size_t)b * (T_ * D_);

    // ---- stage X tile (float4 load -> pack4h -> b64 swizzled store) ----
    {
        const int cr = (tid & 31) << 2;
        for (int j = (tid >> 5); j < 66; j += 16) {
            const int tg = (t0 + j - 1) & (T_ - 1);
            const f32x4 v = *reinterpret_cast<const f32x4*>(srcb + tg * D_ + cr);
            int byte = (j * 128 + cr) * 2;
            byte ^= (j & 7) << 4;
            *reinterpret_cast<unsigned long long*>(reinterpret_cast<char*>(Xs) + byte) =
                pack4h(v[0], v[1], v[2], v[3]);
        }
    }
    __syncthreads();   // staging must land (full barrier once)

    const int wave = tid >> 6;           // 0..7
    const int lane = tid & 63;
    const int l16 = lane & 15;
    const int lhi = lane >> 4;
    const int kbase = lhi * 8;
    const char* Xsb = reinterpret_cast<const char*>(Xs);
    char* Hsb = reinterpret_cast<char*>(Hs);

    const f32x4 z4 = {0.0f, 0.0f, 0.0f, 0.0f};
    f32x4 facc[4];   // [tf] -- wave owns 16 out cols
#pragma unroll
    for (int bq = 0; bq < 4; ++bq) facc[bq] = z4;

#pragma unroll 1
    for (int r = 0; r <= R_; ++r) {
        // ============ stage A: GEMM1(r) -> GELU -> Hs[r&1] ============
        if (r < R_) {
            f32x4 acc1[2][4];   // [nf][tf]  (wave owns H cols [32w, 32w+32))
#pragma unroll
            for (int a = 0; a < 2; ++a)
#pragma unroll
                for (int bq = 0; bq < 4; ++bq) acc1[a][bq] = z4;

            const unsigned short* w1r = W1T + (size_t)r * (256 * 384);

            f16x8 wfr[2][2], xfr[2][4];
            // prologue kk = 0 (seg 0 -> rowadd 1)
#pragma unroll
            for (int nf = 0; nf < 2; ++nf)
                wfr[0][nf] = __builtin_bit_cast(f16x8, *reinterpret_cast<const u16x8*>(
                    w1r + (size_t)(wave * 32 + nf * 16 + l16) * 384 + kbase));
#pragma unroll
            for (int tf = 0; tf < 4; ++tf) {
                const int row = tf * 16 + l16 + 1;
                int byte = row * 256 + kbase * 2;
                byte ^= (row & 7) << 4;
                xfr[0][tf] = __builtin_bit_cast(f16x8,
                    *reinterpret_cast<const u16x8*>(Xsb + byte));
            }

#pragma unroll
            for (int kk = 0; kk < 12; ++kk) {
                const int cur = kk & 1;
                const int nxt = cur ^ 1;
                if (kk < 11) {
                    const int kn = kk + 1;
                    const int segn = kn >> 2;
                    const int rowaddn = (segn == 0) ? 1 : ((segn == 1) ? 0 : 2);
                    const int klocn = ((kn & 3) * 32 + kbase) * 2;
                    const int kgn = kn * 32 + kbase;
#pragma unroll
                    for (int nf = 0; nf < 2; ++nf)
                        wfr[nxt][nf] = __builtin_bit_cast(f16x8,
                            *reinterpret_cast<const u16x8*>(
                                w1r + (size_t)(wave * 32 + nf * 16 + l16) * 384 + kgn));
#pragma unroll
                    for (int tf = 0; tf < 4; ++tf) {
                        const int row = tf * 16 + l16 + rowaddn;
                        int byte = row * 256 + klocn;
                        byte ^= (row & 7) << 4;
                        xfr[nxt][tf] = __builtin_bit_cast(f16x8,
                            *reinterpret_cast<const u16x8*>(Xsb + byte));
                    }
                }
#pragma unroll
                for (int nf = 0; nf < 2; ++nf)
#pragma unroll
                    for (int tf = 0; tf < 4; ++tf)
                        acc1[nf][tf] = __builtin_amdgcn_mfma_f32_16x16x32_f16(
                            wfr[cur][nf], xfr[cur][tf], acc1[nf][tf], 0, 0, 0);
            }

            // bias + GELU -> Hs[r&1] (b64 swizzled writes)
            char* hw = Hsb + (r & 1) * 32768;
#pragma unroll
            for (int tf = 0; tf < 4; ++tf) {
                const int t = tf * 16 + l16;
                const int rowbyte = t * 512;
                const int swz = (t & 7) << 4;
#pragma unroll
                for (int nf = 0; nf < 2; ++nf) {
                    const f32x4 bv = *reinterpret_cast<const f32x4*>(
                        b1 + r * 256 + wave * 32 + nf * 16 + lhi * 4);
                    const f32x4 a = acc1[nf][tf];
                    const float g0 = gelu_fast(a[0] + bv[0]);
                    const float g1 = gelu_fast(a[1] + bv[1]);
                    const float g2 = gelu_fast(a[2] + bv[2]);
                    const float g3 = gelu_fast(a[3] + bv[3]);
                    int byte = rowbyte + wave * 64 + nf * 32 + lhi * 8;
                    byte ^= swz;
                    *reinterpret_cast<unsigned long long*>(hw + byte) =
                        pack4h(g0, g1, g2, g3);
                }
            }
        }

        // ============ stage B: GEMM2(r-1) from Hs[(r-1)&1] ============
        if (r > 0) {
            const int rp = r - 1;
            f32x4 acc2[4];   // [tf]  (wave owns O cols [16w, 16w+16))
#pragma unroll
            for (int bq = 0; bq < 4; ++bq) acc2[bq] = z4;

            const unsigned short* w2r = W2T + (size_t)rp * (128 * 256);
            const char* hrd = Hsb + (rp & 1) * 32768;

            f16x8 hfr[2][4], wfr2[2];
            wfr2[0] = __builtin_bit_cast(f16x8, *reinterpret_cast<const u16x8*>(
                w2r + (size_t)(wave * 16 + l16) * 256 + kbase));
#pragma unroll
            for (int tf = 0; tf < 4; ++tf) {
                const int t = tf * 16 + l16;
                int byte = t * 512 + kbase * 2;
                byte ^= (t & 7) << 4;
                hfr[0][tf] = __builtin_bit_cast(f16x8,
                    *reinterpret_cast<const u16x8*>(hrd + byte));
            }

#pragma unroll
            for (int k2 = 0; k2 < 8; ++k2) {
                const int cur = k2 & 1;
                const int nxt = cur ^ 1;
                if (k2 < 7) {
                    const int kgn = (k2 + 1) * 32 + kbase;
                    wfr2[nxt] = __builtin_bit_cast(f16x8, *reinterpret_cast<const u16x8*>(
                        w2r + (size_t)(wave * 16 + l16) * 256 + kgn));
#pragma unroll
                    for (int tf = 0; tf < 4; ++tf) {
                        const int t = tf * 16 + l16;
                        int byte = t * 512 + kgn * 2;
                        byte ^= (t & 7) << 4;
                        hfr[nxt][tf] = __builtin_bit_cast(f16x8,
                            *reinterpret_cast<const u16x8*>(hrd + byte));
                    }
                }
#pragma unroll
                for (int tf = 0; tf < 4; ++tf)
                    acc2[tf] = __builtin_amdgcn_mfma_f32_16x16x32_f16(
                        wfr2[cur], hfr[cur][tf], acc2[tf], 0, 0, 0);
            }

            const float rw = hdr[2 + rp];
            const f32x4 bv = *reinterpret_cast<const f32x4*>(
                b2 + rp * 128 + wave * 16 + lhi * 4);
#pragma unroll
            for (int tf = 0; tf < 4; ++tf)
#pragma unroll
                for (int i = 0; i < 4; ++i)
                    facc[tf][i] += rw * tanh_fast(acc2[tf][i] + bv[i]);
        }

        LDS_BARRIER();   // one LDS-only barrier per rule iteration
    }

    // ---- epilogue: cells = alpha*x + (1-alpha)*new, f32x4 in/out ----
    float* dstb = dst + (size_t)b * (T_ * D_);
    const float om = 1.0f - alpha;
    const int c0 = wave * 16 + lhi * 4;
#pragma unroll
    for (int tf = 0; tf < 4; ++tf) {
        const int t = t0 + tf * 16 + l16;
        const size_t idx = (size_t)t * D_ + c0;
        const f32x4 x = *reinterpret_cast<const f32x4*>(srcb + idx);
        f32x4 o;
#pragma unroll
        for (int i = 0; i < 4; ++i) o[i] = alpha * x[i] + om * facc[tf][i];
        *reinterpret_cast<f32x4*>(dstb + idx) = o;
    }
}

// ---------------------------------------------------------------------------
// LayerNorm over D=128. One wave per row, 2 elems/lane.
// ---------------------------------------------------------------------------
__global__ __launch_bounds__(256) void ln_kernel(
    const float* __restrict__ buf0, const float* __restrict__ buf1,
    const float* __restrict__ hdr,
    const float* __restrict__ g, const float* __restrict__ bb,
    float* __restrict__ out)
{
    const int ne = (int)hdr[0];
    const float* src = ((ne - 1) & 1) ? buf1 : buf0;   // step s writes buf[s&1]
    const int row = blockIdx.x * 4 + (threadIdx.x >> 6);
    const int lane = threadIdx.x & 63;
    const size_t base = (size_t)row * D_;
    const int d = lane * 2;
    const float a = src[base + d];
    const float c = src[base + d + 1];
    float s = a + c;
    float q = a * a + c * c;
#pragma unroll
    for (int off = 32; off >= 1; off >>= 1) {
        s += __shfl_xor(s, off);
        q += __shfl_xor(q, off);
    }
    const float mean = s * (1.0f / 128.0f);
    float var = q * (1.0f / 128.0f) - mean * mean;
    var = fmaxf(var, 0.0f);
    const float rstd = rsqrtf(var + 1e-5f);
    out[base + d]     = (a - mean) * rstd * g[d] + bb[d];
    out[base + d + 1] = (c - mean) * rstd * g[d + 1] + bb[d + 1];
}

// ---------------------------------------------------------------------------
extern "C" void kernel_launch(void* const* d_in, const int* in_sizes, int n_in,
                              void* d_out, int out_size, void* d_ws, size_t ws_size,
                              hipStream_t stream)
{
    (void)in_sizes; (void)n_in; (void)out_size; (void)ws_size;
    const float* cells  = (const float*)d_in[0];
    const float* cst    = (const float*)d_in[1];
    const float* W1     = (const float*)d_in[2];
    const float* b1     = (const float*)d_in[3];
    const float* W2     = (const float*)d_in[4];
    const float* b2     = (const float*)d_in[5];
    const float* rW1    = (const float*)d_in[6];
    const float* rb1    = (const float*)d_in[7];
    const float* rW2    = (const float*)d_in[8];
    const float* rb2    = (const float*)d_in[9];
    const float* sW1    = (const float*)d_in[10];
    const float* sb1    = (const float*)d_in[11];
    const float* sW2    = (const float*)d_in[12];
    const float* sb2    = (const float*)d_in[13];
    const float* aW1    = (const float*)d_in[14];
    const float* ab1    = (const float*)d_in[15];
    const float* aW2    = (const float*)d_in[16];
    const float* ab2    = (const float*)d_in[17];
    const float* ln_g   = (const float*)d_in[18];
    const float* ln_b   = (const float*)d_in[19];
    float* out = (float*)d_out;

    char* ws = (char*)d_ws;
    float* hdr  = (float*)ws;                                      // 256 B
    float* buf0 = (float*)(ws + 256);                              // 16 MiB
    unsigned short* W1T = (unsigned short*)(ws + 256 + 16777216);  // 1.5 MiB
    unsigned short* W2T = W1T + (size_t)R_ * 256 * 384;            // 0.5 MiB
    float* buf1 = out;  // d_out doubles as ping-pong buffer (LN is in-place safe)

    hipLaunchKernelGGL(prep_weights, dim3(640), dim3(256), 0, stream, W1, W2, W1T, W2T);
    hipLaunchKernelGGL(selectors_kernel, dim3(1), dim3(64), 0, stream,
                       cst, rW1, rb1, rW2, rb2, sW1, sb1, sW2, sb2,
                       aW1, ab1, aW2, ab2, hdr);
    for (int s = 0; s < 8; ++s) {
        hipLaunchKernelGGL(evolve_step, dim3(512), dim3(512), 0, stream,
                           s, cells, buf0, buf1, W1T, W2T, b1, b2, hdr);
    }
    hipLaunchKernelGGL(ln_kernel, dim3(8192), dim3(256), 0, stream,
                       buf0, buf1, hdr, ln_g, ln_b, out);
}